// Round 22
// baseline (215.844 us; speedup 1.0000x reference)
//
#include <hip/hip_runtime.h>

#define DEVFN __device__ __forceinline__

constexpr int B = 4, S = 2048, H = 4, DH = 16, D = 64, F = 256;
constexpr int T = B * S;        // 8192 tokens
constexpr int PAIRS = B * H;    // 16
constexpr int CPP = 72;         // chunk-blocks per pair = sum_{qb=0..15}(qb/2+1)
constexpr int NZ = PAIRS * CPP; // 1152 attention partial blocks
constexpr int PSTRIDE = 1280;   // floats: 128 m + 128 l + 128x16 bf16 acc
constexpr float LOG2E = 1.44269504f;

typedef __attribute__((ext_vector_type(8))) short s16x8;
typedef __attribute__((ext_vector_type(16))) float f32x16;
typedef __attribute__((ext_vector_type(4))) float f32x4;

DEVFN float wave_sum(float v) {
#pragma unroll
    for (int mask = 32; mask >= 1; mask >>= 1)
        v += __shfl_xor(v, mask, 64);
    return v;
}

DEVFN float bf2f(unsigned short u) { return __uint_as_float((unsigned)u << 16); }
DEVFN unsigned short f2bf(float f) {
    unsigned b = __float_as_uint(f);
    return (unsigned short)((b + 0x8000u) >> 16);
}
DEVFN unsigned pack_bf2(float lo, float hi) {
    unsigned a = __float_as_uint(lo), b = __float_as_uint(hi);
    return ((a + 0x8000u) >> 16) | ((b + 0x8000u) & 0xffff0000u);
}
DEVFN unsigned cvtpk(float lo, float hi) {
    unsigned r;
    asm("v_cvt_pk_bf16_f32 %0, %1, %2" : "=v"(r) : "v"(lo), "v"(hi));
    return r;
}
DEVFN void plswap(unsigned& a, unsigned& b) {
#if __has_builtin(__builtin_amdgcn_permlane32_swap)
    typedef unsigned uv2 __attribute__((ext_vector_type(2)));
    uv2 r = __builtin_amdgcn_permlane32_swap(a, b, false, false);
    a = r[0]; b = r[1];
#else
    asm volatile("v_permlane32_swap_b32 %0, %1" : "+v"(a), "+v"(b));
#endif
}

// ---------------------------------------------------------------- kernel 1
// MFMA QKV projection (R20 verbatim) + counter zeroing (block 16).
__global__ __launch_bounds__(256) void k_qkv(
    const float* __restrict__ x,
    const float* __restrict__ wq, const float* __restrict__ bq,
    const float* __restrict__ wk, const float* __restrict__ bk,
    const float* __restrict__ wv, const float* __restrict__ bv,
    const float* __restrict__ wo, const float* __restrict__ w1,
    const float* __restrict__ w2,
    unsigned short* __restrict__ Qb, unsigned short* __restrict__ Kb,
    unsigned short* __restrict__ Vtg,
    unsigned* __restrict__ wob, unsigned* __restrict__ w1b,
    unsigned* __restrict__ w2b, unsigned* __restrict__ cnt)
{
    __shared__ __align__(16) unsigned short xfr[2][2][64][8];   // 4 KB
    __shared__ __align__(16) unsigned short wfr[12][2][64][8];  // 24 KB

    int tid = threadIdx.x, lane = tid & 63, w = tid >> 6;
    int t0 = blockIdx.x * 32;
    int b = t0 >> 11;
    int sbase = t0 & (S - 1);

    if (blockIdx.x == 16 && tid < 64) cnt[tid] = 0;   // ticket counters

#pragma unroll
    for (int e = 0; e < 4; ++e) {
        int i = e * 256 + tid;
        int tt = i >> 9, ks = (i >> 8) & 1, l = (i >> 2) & 63, ee = 2 * (i & 3);
        int token = 16 * tt + (l & 15);
        int kk = 32 * ks + 8 * (l >> 4) + ee;
        float2 xv = *(const float2*)(x + (size_t)(t0 + token) * D + kk);
        *(unsigned*)&xfr[tt][ks][l][ee] = pack_bf2(xv.x, xv.y);
    }
#pragma unroll
    for (int e = 0; e < 24; ++e) {
        int i = e * 256 + tid;
        int combo = i >> 9, ks = (i >> 8) & 1, l = (i >> 2) & 63, ee = 2 * (i & 3);
        int m = combo >> 2, jt = combo & 3;
        int j15 = l & 15;
        int kk = 32 * ks + 8 * (l >> 4) + ee;
        const float* wsrc = (m == 0) ? wq : (m == 1) ? wk : wv;
        float a = wsrc[jt * 1024 + kk * 16 + j15];
        float c = wsrc[jt * 1024 + (kk + 1) * 16 + j15];
        *(unsigned*)&wfr[combo][ks][l][ee] = pack_bf2(a, c);
    }

    if (blockIdx.x < 16) {            // one-time post fragment weight build
        int bi = blockIdx.x;
        if (tid < 128) {
            int i = bi * 128 + tid;
            int jt = i >> 9, ks = (i >> 8) & 1, l = (i >> 2) & 63, ee = 2 * (i & 3);
            int j = 16 * jt + (l & 15);
            int k = 32 * ks + 8 * (l >> 4) + ee;
            wob[i] = pack_bf2(wo[k * D + j], wo[(k + 1) * D + j]);
        }
#pragma unroll
        for (int e = 0; e < 2; ++e) {
            int i = bi * 512 + e * 256 + tid;
            int ft = i >> 9, ks = (i >> 8) & 1, l = (i >> 2) & 63, ee = 2 * (i & 3);
            int f = 16 * ft + (l & 15);
            int k = 32 * ks + 8 * (l >> 4) + ee;
            w1b[i] = pack_bf2(w1[k * F + f], w1[(k + 1) * F + f]);
        }
#pragma unroll
        for (int e = 0; e < 2; ++e) {
            int i = bi * 512 + e * 256 + tid;
            int jt = i >> 11, ks = (i >> 8) & 7, l = (i >> 2) & 63, ee = 2 * (i & 3);
            int j = 16 * jt + (l & 15);
            int k = 32 * ks + 8 * (l >> 4) + ee;
            w2b[i] = pack_bf2(w2[k * D + j], w2[(k + 1) * D + j]);
        }
    }
    __syncthreads();

    int j15 = lane & 15, q4 = lane >> 4;
#pragma unroll
    for (int t3 = 0; t3 < 3; ++t3) {
        int combo = w * 3 + t3;
        int m = combo >> 2, jt = combo & 3;
        int j = 16 * jt + j15;
        int pair = b * H + jt;
#pragma unroll
        for (int tt = 0; tt < 2; ++tt) {
            f32x4 c = {0.f, 0.f, 0.f, 0.f};
#pragma unroll
            for (int ks = 0; ks < 2; ++ks) {
                s16x8 af = *(const s16x8*)&xfr[tt][ks][lane][0];
                s16x8 bf = *(const s16x8*)&wfr[combo][ks][lane][0];
                c = __builtin_amdgcn_mfma_f32_16x16x32_bf16(af, bf, c, 0, 0, 0);
            }
            int s0 = sbase + 16 * tt + 4 * q4;
            if (m == 0) {
                float bj = bq[j];
#pragma unroll
                for (int r = 0; r < 4; ++r)
                    Qb[((size_t)pair * S + s0 + r) * DH + j15] =
                        f2bf((c[r] + bj) * (0.25f * LOG2E));
            } else if (m == 1) {
                float bj = bk[j];
#pragma unroll
                for (int r = 0; r < 4; ++r)
                    Kb[((size_t)pair * S + s0 + r) * DH + j15] = f2bf(c[r] + bj);
            } else {
                float bj = bv[j];
                uint2 o;
                o.x = pack_bf2(c[0] + bj, c[1] + bj);
                o.y = pack_bf2(c[2] + bj, c[3] + bj);
                *(uint2*)(Vtg + ((size_t)pair * DH + j15) * S + s0) = o;
            }
        }
    }
}

// ---------------------------------------------------------------- kernel 2
// MFMA flash attention partial (R21) + last-arrival ticket -> fused post.
// The block completing a 128-token group's last P slice runs merge+oproj+
// LN1+FFN+LN2 for that group (8 x 16-token sub-blocks, LDS via union).
__global__ __launch_bounds__(256, 4) void k_attn(
    const unsigned short* __restrict__ Qb, const unsigned short* __restrict__ Kb,
    const unsigned short* __restrict__ Vtg, float* __restrict__ P,
    const float* __restrict__ x,
    const unsigned* __restrict__ wob, const float* __restrict__ bo,
    const float* __restrict__ g1, const float* __restrict__ bb1,
    const unsigned* __restrict__ w1b, const float* __restrict__ b1,
    const unsigned* __restrict__ w2b, const float* __restrict__ b2,
    const float* __restrict__ g2, const float* __restrict__ bb2,
    unsigned* __restrict__ cnt, float* __restrict__ out)
{
    union SH {
        struct { unsigned short Kt[256][16]; unsigned short Vt[16][264]; } a;
        struct {
            unsigned short Asb[16][72];
            float Os[16][68];
            float R1s[16][68];
            unsigned short R1sb[16][72];
            unsigned short Hhb[16][264];
        } p;
    };
    __shared__ __align__(16) SH sh;
    __shared__ int winner;

    int tid = threadIdx.x, lane = tid & 63, w = tid >> 6;

    int bid0 = blockIdx.x;
    int z = (bid0 & 7) * 144 + (bid0 >> 3);  // XCD-bijective swizzle
    int pair = z / CPP;
    int rem = z - pair * CPP;
    int qb = 0, cum = 0;
    while (cum + (qb >> 1) + 1 <= rem) { cum += (qb >> 1) + 1; ++qb; }
    int kc = rem - cum;
    int kbase = kc << 8;
    int qbase = qb << 7;

    {
        const uint4* src = (const uint4*)(Kb + (size_t)(pair * S + kbase + tid) * DH);
        uint4 lo = src[0], hi = src[1];
        *(uint4*)&sh.a.Kt[tid][(tid & 1) * 8] = lo;
        *(uint4*)&sh.a.Kt[tid][((tid & 1) ^ 1) * 8] = hi;
        int r = tid >> 4, cc = tid & 15;
        const uint4* vs = (const uint4*)(Vtg + (size_t)(pair * DH + r) * S + kbase + cc * 16);
        uint4 v0 = vs[0], v1 = vs[1];
        *(uint4*)&sh.a.Vt[r][cc * 16] = v0;
        *(uint4*)&sh.a.Vt[r][cc * 16 + 8] = v1;
    }
    __syncthreads();

    int qn = lane & 31, g = lane >> 5;
    int q0w = qbase + w * 32;
    int qg = q0w + qn;
    int vrow = lane & 15;

    s16x8 qf = *(const s16x8*)(Qb + (size_t)(pair * S + qg) * DH + g * 8);

    f32x16 czero;
#pragma unroll
    for (int i = 0; i < 16; ++i) czero[i] = 0.f;
    f32x16 acc = czero;
    float mrun = -1e30f, lsum = 0.f;

    int nt = ((q0w + 31 - kbase) >> 5) + 1;
    if (nt > 8) nt = 8;
    int ntt = (nt + 1) >> 1;          // 64-key super-tiles

    for (int u = 0; u < ntt; ++u) {
        int kl = u * 64;
        int krowA = kl + qn, krowB = kl + 32 + qn;
        s16x8 kf0 = *(const s16x8*)&sh.a.Kt[krowA][(g ^ (krowA & 1)) * 8];
        s16x8 kf1 = *(const s16x8*)&sh.a.Kt[krowB][(g ^ (krowB & 1)) * 8];
        s16x8 vfa0 = *(const s16x8*)&sh.a.Vt[vrow][kl + g * 8];
        s16x8 vfa1 = *(const s16x8*)&sh.a.Vt[vrow][kl + 16 + g * 8];
        s16x8 vfb0 = *(const s16x8*)&sh.a.Vt[vrow][kl + 32 + g * 8];
        s16x8 vfb1 = *(const s16x8*)&sh.a.Vt[vrow][kl + 48 + g * 8];

        f32x16 sc0 = __builtin_amdgcn_mfma_f32_32x32x16_bf16(kf0, qf, czero, 0, 0, 0);
        f32x16 sc1 = __builtin_amdgcn_mfma_f32_32x32x16_bf16(kf1, qf, czero, 0, 0, 0);

        if (u == ntt - 1) {               // wave-uniform diagonal/tail mask
            int qml0 = qg - (kbase + kl);
            int qml1 = qml0 - 32;
#pragma unroll
            for (int r = 0; r < 16; ++r) {
                int m = (r & 3) + 8 * (r >> 2) + 4 * g;
                sc0[r] = (m <= qml0) ? sc0[r] : -1e30f;
                sc1[r] = (m <= qml1) ? sc1[r] : -1e30f;
            }
        }
        float mx[8];
#pragma unroll
        for (int r = 0; r < 8; ++r)
            mx[r] = fmaxf(fmaxf(sc0[r], sc0[r + 8]), fmaxf(sc1[r], sc1[r + 8]));
        float tm = fmaxf(fmaxf(fmaxf(mx[0], mx[1]), fmaxf(mx[2], mx[3])),
                         fmaxf(fmaxf(mx[4], mx[5]), fmaxf(mx[6], mx[7])));
        tm = fmaxf(tm, __shfl_xor(tm, 32, 64));

        if (__any(tm > mrun + 8.f)) {     // deferred rescale (T13)
            float mnew = fmaxf(mrun, tm);
            float scale = exp2f(mrun - mnew);
            mrun = mnew;
            lsum *= scale;
#pragma unroll
            for (int r = 0; r < 8; ++r) acc[r] *= scale;
        }
        float ts0 = 0.f, ts1 = 0.f, ts2 = 0.f, ts3 = 0.f;
#pragma unroll
        for (int r = 0; r < 16; r += 4) {
            sc0[r]     = exp2f(sc0[r] - mrun);     ts0 += sc0[r];
            sc0[r + 1] = exp2f(sc0[r + 1] - mrun); ts1 += sc0[r + 1];
            sc0[r + 2] = exp2f(sc0[r + 2] - mrun); ts2 += sc0[r + 2];
            sc0[r + 3] = exp2f(sc0[r + 3] - mrun); ts3 += sc0[r + 3];
        }
#pragma unroll
        for (int r = 0; r < 16; r += 4) {
            sc1[r]     = exp2f(sc1[r] - mrun);     ts0 += sc1[r];
            sc1[r + 1] = exp2f(sc1[r + 1] - mrun); ts1 += sc1[r + 1];
            sc1[r + 2] = exp2f(sc1[r + 2] - mrun); ts2 += sc1[r + 2];
            sc1[r + 3] = exp2f(sc1[r + 3] - mrun); ts3 += sc1[r + 3];
        }
        float ts = (ts0 + ts1) + (ts2 + ts3);
        ts += __shfl_xor(ts, 32, 64);
        lsum += ts;

        unsigned a0 = cvtpk(sc0[0],  sc0[1]);
        unsigned a1 = cvtpk(sc0[2],  sc0[3]);
        unsigned a2 = cvtpk(sc0[4],  sc0[5]);
        unsigned a3 = cvtpk(sc0[6],  sc0[7]);
        unsigned b0 = cvtpk(sc0[8],  sc0[9]);
        unsigned b1 = cvtpk(sc0[10], sc0[11]);
        unsigned b2 = cvtpk(sc0[12], sc0[13]);
        unsigned b3 = cvtpk(sc0[14], sc0[15]);
        plswap(a0, a2); plswap(a1, a3); plswap(b0, b2); plswap(b1, b3);
        unsigned c0 = cvtpk(sc1[0],  sc1[1]);
        unsigned c1 = cvtpk(sc1[2],  sc1[3]);
        unsigned c2 = cvtpk(sc1[4],  sc1[5]);
        unsigned c3 = cvtpk(sc1[6],  sc1[7]);
        unsigned d0 = cvtpk(sc1[8],  sc1[9]);
        unsigned d1 = cvtpk(sc1[10], sc1[11]);
        unsigned d2 = cvtpk(sc1[12], sc1[13]);
        unsigned d3 = cvtpk(sc1[14], sc1[15]);
        plswap(c0, c2); plswap(c1, c3); plswap(d0, d2); plswap(d1, d3);

        union UU { unsigned u[4]; s16x8 v; };
        UU pf0, pf1, pf2, pf3;
        pf0.u[0] = a0; pf0.u[1] = a1; pf0.u[2] = a2; pf0.u[3] = a3;
        pf1.u[0] = b0; pf1.u[1] = b1; pf1.u[2] = b2; pf1.u[3] = b3;
        pf2.u[0] = c0; pf2.u[1] = c1; pf2.u[2] = c2; pf2.u[3] = c3;
        pf3.u[0] = d0; pf3.u[1] = d1; pf3.u[2] = d2; pf3.u[3] = d3;

        acc = __builtin_amdgcn_mfma_f32_32x32x16_bf16(vfa0, pf0.v, acc, 0, 0, 0);
        acc = __builtin_amdgcn_mfma_f32_32x32x16_bf16(vfa1, pf1.v, acc, 0, 0, 0);
        acc = __builtin_amdgcn_mfma_f32_32x32x16_bf16(vfb0, pf2.v, acc, 0, 0, 0);
        acc = __builtin_amdgcn_mfma_f32_32x32x16_bf16(vfb1, pf3.v, acc, 0, 0, 0);
    }

    {
        float* base = P + (size_t)z * PSTRIDE;
        if (lane < 32) {
            base[w * 32 + qn] = mrun;            // log2-domain max
            base[128 + w * 32 + qn] = lsum;
        }
        uint2 cA, cB;
        cA.x = pack_bf2(acc[0], acc[1]); cA.y = pack_bf2(acc[2], acc[3]);
        cB.x = pack_bf2(acc[4], acc[5]); cB.y = pack_bf2(acc[6], acc[7]);
        unsigned short* pa = (unsigned short*)(base + 256);
        *(uint2*)&pa[(w * 32 + qn) * 16 + 4 * g] = cA;
        *(uint2*)&pa[(w * 32 + qn) * 16 + 8 + 4 * g] = cB;
    }

    // ---- last-arrival ticket: the block completing this 128-token group
    // (4 pairs x nc chunks) runs the fused post for it.
    __threadfence();                      // release own P stores
    __syncthreads();                      // order all waves' fences
    int grp = (pair >> 2) * 16 + qb;      // (batch, qb) group, 0..63
    if (tid == 0) {
        int need = 4 * ((qb >> 1) + 1);
        unsigned old = atomicAdd(&cnt[grp], 1u);
        winner = (old == (unsigned)(need - 1)) ? 1 : 0;
    }
    __syncthreads();
    if (!winner) return;
    __threadfence();                      // acquire: see other blocks' P

    // ================= fused post for tokens grp*128 .. +128 ==========
    for (int sub = 0; sub < 8; ++sub) {
        int t0 = grp * 128 + sub * 16;
        int b = t0 >> 11;
        int sbase = t0 & (S - 1);
        int qbp = sbase >> 7;
        int nc = (qbp >> 1) + 1;
        int cumP = 0;
#pragma unroll
        for (int i = 0; i < 16; ++i) cumP += (i < qbp) ? ((i >> 1) + 1) : 0;

        // phase 1: merge split-K partials -> Asb (bf16)
        {
            int token = tid >> 4, sub2 = tid & 15;
            int h = sub2 >> 2, dq = sub2 & 3;
            int pr = b * H + h;
            int q = (sbase & 127) + token;
            const float* base0 = P + ((size_t)pr * CPP + cumP) * PSTRIDE;

            float mv[8], sv[8]; uint2 uv[8];
#pragma unroll
            for (int c = 0; c < 8; ++c) {
                int cc = (c < nc) ? c : (nc - 1);
                const float* bc = base0 + cc * PSTRIDE;
                float m_ = bc[q];
                float s_ = bc[128 + q];
                uint2 u_ = *(const uint2*)((const unsigned*)(bc + 256) + q * 8 + dq * 2);
                bool valid = (c < nc);
                mv[c] = valid ? m_ : -1e30f;
                sv[c] = valid ? s_ : 0.f;
                uv[c].x = valid ? u_.x : 0u;
                uv[c].y = valid ? u_.y : 0u;
            }
            float M = fmaxf(fmaxf(fmaxf(mv[0], mv[1]), fmaxf(mv[2], mv[3])),
                            fmaxf(fmaxf(mv[4], mv[5]), fmaxf(mv[6], mv[7])));
            float Sm = 0.f, a0 = 0.f, a1 = 0.f, a2 = 0.f, a3 = 0.f;
#pragma unroll
            for (int c = 0; c < 8; ++c) {
                float e = exp2f(mv[c] - M);
                Sm = fmaf(sv[c], e, Sm);
                a0 = fmaf(__uint_as_float(uv[c].x << 16), e, a0);
                a1 = fmaf(__uint_as_float(uv[c].x & 0xffff0000u), e, a1);
                a2 = fmaf(__uint_as_float(uv[c].y << 16), e, a2);
                a3 = fmaf(__uint_as_float(uv[c].y & 0xffff0000u), e, a3);
            }
            float inv = 1.f / Sm;
            uint2 o;
            o.x = cvtpk(a0 * inv, a1 * inv);
            o.y = cvtpk(a2 * inv, a3 * inv);
            *(uint2*)&sh.p.Asb[token][16 * h + 4 * dq] = o;
        }
        __syncthreads();

        // phase 2: oproj MFMA + bias + residual -> Os
        {
            f32x4 c = {0.f, 0.f, 0.f, 0.f};
#pragma unroll
            for (int ks = 0; ks < 2; ++ks) {
                s16x8 af = *(const s16x8*)&sh.p.Asb[lane & 15][32 * ks + 8 * (lane >> 4)];
                s16x8 bf = *(const s16x8*)(wob + (((w * 2) + ks) * 64 + lane) * 4);
                c = __builtin_amdgcn_mfma_f32_16x16x32_bf16(af, bf, c, 0, 0, 0);
            }
            int j = 16 * w + (lane & 15);
            int q4 = lane >> 4;
            float boj = bo[j];
#pragma unroll
            for (int r = 0; r < 4; ++r) {
                int tk = q4 * 4 + r;
                sh.p.Os[tk][j] = c[r] + boj + x[(size_t)(t0 + tk) * D + j];
            }
        }
        __syncthreads();

        // phase 3: LN1 -> R1s + R1sb
        {
            int j = lane;
            float gj = g1[j], bj = bb1[j];
#pragma unroll
            for (int i = 0; i < 4; ++i) {
                int tk = w * 4 + i;
                float o = sh.p.Os[tk][j];
                float mu = wave_sum(o) * (1.f / 64.f);
                float dif = o - mu;
                float var = wave_sum(dif * dif) * (1.f / 64.f);
                float r1 = dif * rsqrtf(var + 1e-5f) * gj + bj;
                sh.p.R1s[tk][j] = r1;
                sh.p.R1sb[tk][j] = f2bf(r1);
            }
        }
        __syncthreads();

        // phase 4: FFN1 MFMA + b1 + relu -> Hhb
        {
            int q4 = lane >> 4;
#pragma unroll
            for (int t = 0; t < 4; ++t) {
                int ft = w * 4 + t;
                f32x4 c = {0.f, 0.f, 0.f, 0.f};
#pragma unroll
                for (int ks = 0; ks < 2; ++ks) {
                    s16x8 af = *(const s16x8*)&sh.p.R1sb[lane & 15][32 * ks + 8 * (lane >> 4)];
                    s16x8 bf = *(const s16x8*)(w1b + (((ft * 2) + ks) * 64 + lane) * 4);
                    c = __builtin_amdgcn_mfma_f32_16x16x32_bf16(af, bf, c, 0, 0, 0);
                }
                int f = 16 * ft + (lane & 15);
                float b1f = b1[f];
#pragma unroll
                for (int r = 0; r < 4; ++r)
                    sh.p.Hhb[q4 * 4 + r][f] = f2bf(fmaxf(c[r] + b1f, 0.f));
            }
        }
        __syncthreads();

        // phase 5: FFN2 MFMA + b2 + residual -> Os (reused as Ys)
        {
            f32x4 c = {0.f, 0.f, 0.f, 0.f};
#pragma unroll
            for (int ks = 0; ks < 8; ++ks) {
                s16x8 af = *(const s16x8*)&sh.p.Hhb[lane & 15][32 * ks + 8 * (lane >> 4)];
                s16x8 bf = *(const s16x8*)(w2b + (((w * 8) + ks) * 64 + lane) * 4);
                c = __builtin_amdgcn_mfma_f32_16x16x32_bf16(af, bf, c, 0, 0, 0);
            }
            int j = 16 * w + (lane & 15);
            int q4 = lane >> 4;
            float b2j = b2[j];
#pragma unroll
            for (int r = 0; r < 4; ++r) {
                int tk = q4 * 4 + r;
                sh.p.Os[tk][j] = c[r] + b2j + sh.p.R1s[tk][j];
            }
        }
        __syncthreads();

        // phase 6: LN2 -> out
        {
            int j = lane;
            float gj = g2[j], bj = bb2[j];
#pragma unroll
            for (int i = 0; i < 4; ++i) {
                int tk = w * 4 + i;
                float y = sh.p.Os[tk][j];
                float mu = wave_sum(y) * (1.f / 64.f);
                float dif = y - mu;
                float var = wave_sum(dif * dif) * (1.f / 64.f);
                out[(size_t)(t0 + tk) * D + j] = dif * rsqrtf(var + 1e-5f) * gj + bj;
            }
        }
        __syncthreads();
    }
}

// ----------------------------------------------------------------
extern "C" void kernel_launch(void* const* d_in, const int* in_sizes, int n_in,
                              void* d_out, int out_size, void* d_ws, size_t ws_size,
                              hipStream_t stream)
{
    const float* x   = (const float*)d_in[0];
    const float* wq  = (const float*)d_in[1];
    const float* bq  = (const float*)d_in[2];
    const float* wk  = (const float*)d_in[3];
    const float* bk  = (const float*)d_in[4];
    const float* wv  = (const float*)d_in[5];
    const float* bv  = (const float*)d_in[6];
    const float* wo  = (const float*)d_in[7];
    const float* bo  = (const float*)d_in[8];
    const float* g1  = (const float*)d_in[9];
    const float* be1 = (const float*)d_in[10];
    const float* w1  = (const float*)d_in[11];
    const float* b1  = (const float*)d_in[12];
    const float* w2  = (const float*)d_in[13];
    const float* b2  = (const float*)d_in[14];
    const float* g2  = (const float*)d_in[15];
    const float* be2 = (const float*)d_in[16];

    char* base = (char*)d_ws;
    unsigned short* Qb  = (unsigned short*)base;                  // 1 MB
    unsigned short* Kb  = (unsigned short*)(base + (1u << 20));   // 1 MB
    unsigned short* Vtg = (unsigned short*)(base + (2u << 20));   // 1 MB
    float*          P   = (float*)(base + (3u << 20));            // 5.9 MB
    unsigned*       wob = (unsigned*)(base + (9u << 20));         // 8 KB
    unsigned*       w1b = (unsigned*)(base + (9u << 20) + 0x10000); // 32 KB
    unsigned*       w2b = (unsigned*)(base + (9u << 20) + 0x20000); // 32 KB
    unsigned*       cnt = (unsigned*)(base + (9u << 20) + 0x30000); // 256 B

    k_qkv <<<T / 32, 256, 0, stream>>>(x, wq, bq, wk, bk, wv, bv,
                                       wo, w1, w2, Qb, Kb, Vtg,
                                       wob, w1b, w2b, cnt);
    k_attn<<<NZ, 256, 0, stream>>>(Qb, Kb, Vtg, P, x,
                                   wob, bo, g1, be1, w1b, b1, w2b, b2,
                                   g2, be2, cnt, (float*)d_out);
}

// Round 23
// 37.897 us; speedup vs baseline: 5.6956x; 5.6956x over previous
//
#include <hip/hip_runtime.h>

#define DEVFN __device__ __forceinline__

constexpr int B = 4, S = 2048, H = 4, DH = 16, D = 64, F = 256;
constexpr int T = B * S;        // 8192 tokens
constexpr int PAIRS = B * H;    // 16
constexpr int CPP = 72;         // chunk-blocks per pair = sum_{qb=0..15}(qb/2+1)
constexpr int NZ = PAIRS * CPP; // 1152 attention partial blocks
constexpr int PSTRIDE = 1280;   // floats: 128 m + 128 l + 128x16 bf16 acc
constexpr float LOG2E = 1.44269504f;

typedef __attribute__((ext_vector_type(8))) short s16x8;
typedef __attribute__((ext_vector_type(16))) float f32x16;
typedef __attribute__((ext_vector_type(4))) float f32x4;

DEVFN float wave_sum(float v) {
#pragma unroll
    for (int mask = 32; mask >= 1; mask >>= 1)
        v += __shfl_xor(v, mask, 64);
    return v;
}

DEVFN float bf2f(unsigned short u) { return __uint_as_float((unsigned)u << 16); }
DEVFN unsigned short f2bf(float f) {
    unsigned b = __float_as_uint(f);
    return (unsigned short)((b + 0x8000u) >> 16);
}
DEVFN unsigned pack_bf2(float lo, float hi) {
    unsigned a = __float_as_uint(lo), b = __float_as_uint(hi);
    return ((a + 0x8000u) >> 16) | ((b + 0x8000u) & 0xffff0000u);
}
DEVFN unsigned cvtpk(float lo, float hi) {
    unsigned r;
    asm("v_cvt_pk_bf16_f32 %0, %1, %2" : "=v"(r) : "v"(lo), "v"(hi));
    return r;
}
DEVFN void plswap(unsigned& a, unsigned& b) {
#if __has_builtin(__builtin_amdgcn_permlane32_swap)
    typedef unsigned uv2 __attribute__((ext_vector_type(2)));
    uv2 r = __builtin_amdgcn_permlane32_swap(a, b, false, false);
    a = r[0]; b = r[1];
#else
    asm volatile("v_permlane32_swap_b32 %0, %1" : "+v"(a), "+v"(b));
#endif
}

// ---------------------------------------------------------------- kernel 1
// MFMA QKV projection (R20/R21 verbatim), 32 tokens per block.
__global__ __launch_bounds__(256) void k_qkv(
    const float* __restrict__ x,
    const float* __restrict__ wq, const float* __restrict__ bq,
    const float* __restrict__ wk, const float* __restrict__ bk,
    const float* __restrict__ wv, const float* __restrict__ bv,
    const float* __restrict__ wo, const float* __restrict__ w1,
    const float* __restrict__ w2,
    unsigned short* __restrict__ Qb, unsigned short* __restrict__ Kb,
    unsigned short* __restrict__ Vtg,
    unsigned* __restrict__ wob, unsigned* __restrict__ w1b,
    unsigned* __restrict__ w2b)
{
    __shared__ __align__(16) unsigned short xfr[2][2][64][8];   // 4 KB
    __shared__ __align__(16) unsigned short wfr[12][2][64][8];  // 24 KB

    int tid = threadIdx.x, lane = tid & 63, w = tid >> 6;
    int t0 = blockIdx.x * 32;
    int b = t0 >> 11;
    int sbase = t0 & (S - 1);

#pragma unroll
    for (int e = 0; e < 4; ++e) {
        int i = e * 256 + tid;
        int tt = i >> 9, ks = (i >> 8) & 1, l = (i >> 2) & 63, ee = 2 * (i & 3);
        int token = 16 * tt + (l & 15);
        int kk = 32 * ks + 8 * (l >> 4) + ee;
        float2 xv = *(const float2*)(x + (size_t)(t0 + token) * D + kk);
        *(unsigned*)&xfr[tt][ks][l][ee] = pack_bf2(xv.x, xv.y);
    }
#pragma unroll
    for (int e = 0; e < 24; ++e) {
        int i = e * 256 + tid;
        int combo = i >> 9, ks = (i >> 8) & 1, l = (i >> 2) & 63, ee = 2 * (i & 3);
        int m = combo >> 2, jt = combo & 3;
        int j15 = l & 15;
        int kk = 32 * ks + 8 * (l >> 4) + ee;
        const float* wsrc = (m == 0) ? wq : (m == 1) ? wk : wv;
        float a = wsrc[jt * 1024 + kk * 16 + j15];
        float c = wsrc[jt * 1024 + (kk + 1) * 16 + j15];
        *(unsigned*)&wfr[combo][ks][l][ee] = pack_bf2(a, c);
    }

    if (blockIdx.x < 16) {            // one-time k_post fragment weight build
        int bi = blockIdx.x;
        if (tid < 128) {
            int i = bi * 128 + tid;
            int jt = i >> 9, ks = (i >> 8) & 1, l = (i >> 2) & 63, ee = 2 * (i & 3);
            int j = 16 * jt + (l & 15);
            int k = 32 * ks + 8 * (l >> 4) + ee;
            wob[i] = pack_bf2(wo[k * D + j], wo[(k + 1) * D + j]);
        }
#pragma unroll
        for (int e = 0; e < 2; ++e) {
            int i = bi * 512 + e * 256 + tid;
            int ft = i >> 9, ks = (i >> 8) & 1, l = (i >> 2) & 63, ee = 2 * (i & 3);
            int f = 16 * ft + (l & 15);
            int k = 32 * ks + 8 * (l >> 4) + ee;
            w1b[i] = pack_bf2(w1[k * F + f], w1[(k + 1) * F + f]);
        }
#pragma unroll
        for (int e = 0; e < 2; ++e) {
            int i = bi * 512 + e * 256 + tid;
            int jt = i >> 11, ks = (i >> 8) & 7, l = (i >> 2) & 63, ee = 2 * (i & 3);
            int j = 16 * jt + (l & 15);
            int k = 32 * ks + 8 * (l >> 4) + ee;
            w2b[i] = pack_bf2(w2[k * D + j], w2[(k + 1) * D + j]);
        }
    }
    __syncthreads();

    int j15 = lane & 15, q4 = lane >> 4;
#pragma unroll
    for (int t3 = 0; t3 < 3; ++t3) {
        int combo = w * 3 + t3;
        int m = combo >> 2, jt = combo & 3;
        int j = 16 * jt + j15;
        int pair = b * H + jt;
#pragma unroll
        for (int tt = 0; tt < 2; ++tt) {
            f32x4 c = {0.f, 0.f, 0.f, 0.f};
#pragma unroll
            for (int ks = 0; ks < 2; ++ks) {
                s16x8 af = *(const s16x8*)&xfr[tt][ks][lane][0];
                s16x8 bf = *(const s16x8*)&wfr[combo][ks][lane][0];
                c = __builtin_amdgcn_mfma_f32_16x16x32_bf16(af, bf, c, 0, 0, 0);
            }
            int s0 = sbase + 16 * tt + 4 * q4;
            if (m == 0) {
                float bj = bq[j];
#pragma unroll
                for (int r = 0; r < 4; ++r)
                    Qb[((size_t)pair * S + s0 + r) * DH + j15] =
                        f2bf((c[r] + bj) * (0.25f * LOG2E));
            } else if (m == 1) {
                float bj = bk[j];
#pragma unroll
                for (int r = 0; r < 4; ++r)
                    Kb[((size_t)pair * S + s0 + r) * DH + j15] = f2bf(c[r] + bj);
            } else {
                float bj = bv[j];
                uint2 o;
                o.x = pack_bf2(c[0] + bj, c[1] + bj);
                o.y = pack_bf2(c[2] + bj, c[3] + bj);
                *(uint2*)(Vtg + ((size_t)pair * DH + j15) * S + s0) = o;
            }
        }
    }
}

// ---------------------------------------------------------------- kernel 2
// MFMA flash attention partial (R21) + s_setprio around MFMA clusters
// (T5: independent barrier-free blocks at diverse phases -> scheduler
// favors the MFMA-issuing wave; m191 measured +4-7% on attention).
__global__ __launch_bounds__(256) void k_attn_part(
    const unsigned short* __restrict__ Qb, const unsigned short* __restrict__ Kb,
    const unsigned short* __restrict__ Vtg, float* __restrict__ P)
{
    __shared__ unsigned short Kt[256][16];
    __shared__ unsigned short Vt[16][264];

    int tid = threadIdx.x, lane = tid & 63, w = tid >> 6;

    int bid0 = blockIdx.x;
    int z = (bid0 & 7) * 144 + (bid0 >> 3);  // XCD-bijective swizzle
    int pair = z / CPP;
    int rem = z - pair * CPP;
    int qb = 0, cum = 0;
    while (cum + (qb >> 1) + 1 <= rem) { cum += (qb >> 1) + 1; ++qb; }
    int kc = rem - cum;
    int kbase = kc << 8;
    int qbase = qb << 7;

    {
        const uint4* src = (const uint4*)(Kb + (size_t)(pair * S + kbase + tid) * DH);
        uint4 lo = src[0], hi = src[1];
        *(uint4*)&Kt[tid][(tid & 1) * 8] = lo;
        *(uint4*)&Kt[tid][((tid & 1) ^ 1) * 8] = hi;
        int r = tid >> 4, cc = tid & 15;
        const uint4* vs = (const uint4*)(Vtg + (size_t)(pair * DH + r) * S + kbase + cc * 16);
        uint4 v0 = vs[0], v1 = vs[1];
        *(uint4*)&Vt[r][cc * 16] = v0;
        *(uint4*)&Vt[r][cc * 16 + 8] = v1;
    }
    __syncthreads();

    int qn = lane & 31, g = lane >> 5;
    int q0w = qbase + w * 32;
    int qg = q0w + qn;
    int vrow = lane & 15;

    s16x8 qf = *(const s16x8*)(Qb + (size_t)(pair * S + qg) * DH + g * 8);

    f32x16 czero;
#pragma unroll
    for (int i = 0; i < 16; ++i) czero[i] = 0.f;
    f32x16 acc = czero;
    float mrun = -1e30f, lsum = 0.f;

    int nt = ((q0w + 31 - kbase) >> 5) + 1;
    if (nt > 8) nt = 8;
    int ntt = (nt + 1) >> 1;          // 64-key super-tiles

    for (int u = 0; u < ntt; ++u) {
        int kl = u * 64;
        int krowA = kl + qn, krowB = kl + 32 + qn;
        s16x8 kf0 = *(const s16x8*)&Kt[krowA][(g ^ (krowA & 1)) * 8];
        s16x8 kf1 = *(const s16x8*)&Kt[krowB][(g ^ (krowB & 1)) * 8];
        s16x8 vfa0 = *(const s16x8*)&Vt[vrow][kl + g * 8];
        s16x8 vfa1 = *(const s16x8*)&Vt[vrow][kl + 16 + g * 8];
        s16x8 vfb0 = *(const s16x8*)&Vt[vrow][kl + 32 + g * 8];
        s16x8 vfb1 = *(const s16x8*)&Vt[vrow][kl + 48 + g * 8];

        __builtin_amdgcn_s_setprio(1);
        f32x16 sc0 = __builtin_amdgcn_mfma_f32_32x32x16_bf16(kf0, qf, czero, 0, 0, 0);
        f32x16 sc1 = __builtin_amdgcn_mfma_f32_32x32x16_bf16(kf1, qf, czero, 0, 0, 0);
        __builtin_amdgcn_s_setprio(0);

        if (u == ntt - 1) {               // wave-uniform diagonal/tail mask
            int qml0 = qg - (kbase + kl);
            int qml1 = qml0 - 32;
#pragma unroll
            for (int r = 0; r < 16; ++r) {
                int m = (r & 3) + 8 * (r >> 2) + 4 * g;
                sc0[r] = (m <= qml0) ? sc0[r] : -1e30f;
                sc1[r] = (m <= qml1) ? sc1[r] : -1e30f;
            }
        }
        float mx[8];
#pragma unroll
        for (int r = 0; r < 8; ++r)
            mx[r] = fmaxf(fmaxf(sc0[r], sc0[r + 8]), fmaxf(sc1[r], sc1[r + 8]));
        float tm = fmaxf(fmaxf(fmaxf(mx[0], mx[1]), fmaxf(mx[2], mx[3])),
                         fmaxf(fmaxf(mx[4], mx[5]), fmaxf(mx[6], mx[7])));
        tm = fmaxf(tm, __shfl_xor(tm, 32, 64));

        if (__any(tm > mrun + 8.f)) {     // deferred rescale (T13)
            float mnew = fmaxf(mrun, tm);
            float scale = exp2f(mrun - mnew);
            mrun = mnew;
            lsum *= scale;
#pragma unroll
            for (int r = 0; r < 8; ++r) acc[r] *= scale;
        }
        float ts0 = 0.f, ts1 = 0.f, ts2 = 0.f, ts3 = 0.f;
#pragma unroll
        for (int r = 0; r < 16; r += 4) {
            sc0[r]     = exp2f(sc0[r] - mrun);     ts0 += sc0[r];
            sc0[r + 1] = exp2f(sc0[r + 1] - mrun); ts1 += sc0[r + 1];
            sc0[r + 2] = exp2f(sc0[r + 2] - mrun); ts2 += sc0[r + 2];
            sc0[r + 3] = exp2f(sc0[r + 3] - mrun); ts3 += sc0[r + 3];
        }
#pragma unroll
        for (int r = 0; r < 16; r += 4) {
            sc1[r]     = exp2f(sc1[r] - mrun);     ts0 += sc1[r];
            sc1[r + 1] = exp2f(sc1[r + 1] - mrun); ts1 += sc1[r + 1];
            sc1[r + 2] = exp2f(sc1[r + 2] - mrun); ts2 += sc1[r + 2];
            sc1[r + 3] = exp2f(sc1[r + 3] - mrun); ts3 += sc1[r + 3];
        }
        float ts = (ts0 + ts1) + (ts2 + ts3);
        ts += __shfl_xor(ts, 32, 64);
        lsum += ts;

        unsigned a0 = cvtpk(sc0[0],  sc0[1]);
        unsigned a1 = cvtpk(sc0[2],  sc0[3]);
        unsigned a2 = cvtpk(sc0[4],  sc0[5]);
        unsigned a3 = cvtpk(sc0[6],  sc0[7]);
        unsigned b0 = cvtpk(sc0[8],  sc0[9]);
        unsigned b1 = cvtpk(sc0[10], sc0[11]);
        unsigned b2 = cvtpk(sc0[12], sc0[13]);
        unsigned b3 = cvtpk(sc0[14], sc0[15]);
        plswap(a0, a2); plswap(a1, a3); plswap(b0, b2); plswap(b1, b3);
        unsigned c0 = cvtpk(sc1[0],  sc1[1]);
        unsigned c1 = cvtpk(sc1[2],  sc1[3]);
        unsigned c2 = cvtpk(sc1[4],  sc1[5]);
        unsigned c3 = cvtpk(sc1[6],  sc1[7]);
        unsigned d0 = cvtpk(sc1[8],  sc1[9]);
        unsigned d1 = cvtpk(sc1[10], sc1[11]);
        unsigned d2 = cvtpk(sc1[12], sc1[13]);
        unsigned d3 = cvtpk(sc1[14], sc1[15]);
        plswap(c0, c2); plswap(c1, c3); plswap(d0, d2); plswap(d1, d3);

        union UU { unsigned u[4]; s16x8 v; };
        UU pf0, pf1, pf2, pf3;
        pf0.u[0] = a0; pf0.u[1] = a1; pf0.u[2] = a2; pf0.u[3] = a3;
        pf1.u[0] = b0; pf1.u[1] = b1; pf1.u[2] = b2; pf1.u[3] = b3;
        pf2.u[0] = c0; pf2.u[1] = c1; pf2.u[2] = c2; pf2.u[3] = c3;
        pf3.u[0] = d0; pf3.u[1] = d1; pf3.u[2] = d2; pf3.u[3] = d3;

        __builtin_amdgcn_s_setprio(1);
        acc = __builtin_amdgcn_mfma_f32_32x32x16_bf16(vfa0, pf0.v, acc, 0, 0, 0);
        acc = __builtin_amdgcn_mfma_f32_32x32x16_bf16(vfa1, pf1.v, acc, 0, 0, 0);
        acc = __builtin_amdgcn_mfma_f32_32x32x16_bf16(vfb0, pf2.v, acc, 0, 0, 0);
        acc = __builtin_amdgcn_mfma_f32_32x32x16_bf16(vfb1, pf3.v, acc, 0, 0, 0);
        __builtin_amdgcn_s_setprio(0);
    }

    float* base = P + (size_t)z * PSTRIDE;
    if (lane < 32) {
        base[w * 32 + qn] = mrun;            // log2-domain max
        base[128 + w * 32 + qn] = lsum;
    }
    uint2 cA, cB;
    cA.x = pack_bf2(acc[0], acc[1]); cA.y = pack_bf2(acc[2], acc[3]);
    cB.x = pack_bf2(acc[4], acc[5]); cB.y = pack_bf2(acc[6], acc[7]);
    unsigned short* pa = (unsigned short*)(base + 256);
    *(uint2*)&pa[(w * 32 + qn) * 16 + 4 * g] = cA;
    *(uint2*)&pa[(w * 32 + qn) * 16 + 8 + 4 * g] = cB;
}

// ---------------------------------------------------------------- kernel 3
// MFMA post (R19-R21 verbatim): merge + oproj + LN1 + FFN1 + FFN2 + LN2.
__global__ __launch_bounds__(256) void k_post(
    const float* __restrict__ P, const float* __restrict__ x,
    const unsigned* __restrict__ wob, const float* __restrict__ bo,
    const float* __restrict__ g1, const float* __restrict__ bb1,
    const unsigned* __restrict__ w1b, const float* __restrict__ b1,
    const unsigned* __restrict__ w2b, const float* __restrict__ b2,
    const float* __restrict__ g2, const float* __restrict__ bb2,
    float* __restrict__ out)
{
    __shared__ unsigned short Asb[16][72];
    __shared__ float Os[16][68];
    __shared__ float R1s[16][68];
    __shared__ unsigned short R1sb[16][72];
    __shared__ unsigned short Hhb[16][264];

    int tid = threadIdx.x, lane = tid & 63, w = tid >> 6;
    int t0 = blockIdx.x * 16;
    int b = t0 >> 11;
    int sbase = t0 & (S - 1);
    int qb = sbase >> 7;
    int nc = (qb >> 1) + 1;
    int cum = 0;
#pragma unroll
    for (int i = 0; i < 16; ++i) cum += (i < qb) ? ((i >> 1) + 1) : 0;

    // ---- phase 1: merge split-K partials -> Asb (bf16)
    {
        int token = tid >> 4, sub = tid & 15;
        int h = sub >> 2, dq = sub & 3;
        int pair = b * H + h;
        int q = (sbase & 127) + token;
        const float* base0 = P + ((size_t)pair * CPP + cum) * PSTRIDE;

        float mv[8], sv[8]; uint2 uv[8];
#pragma unroll
        for (int c = 0; c < 8; ++c) {
            int cc = (c < nc) ? c : (nc - 1);
            const float* bc = base0 + cc * PSTRIDE;
            float m_ = bc[q];
            float s_ = bc[128 + q];
            uint2 u_ = *(const uint2*)((const unsigned*)(bc + 256) + q * 8 + dq * 2);
            bool valid = (c < nc);
            mv[c] = valid ? m_ : -1e30f;
            sv[c] = valid ? s_ : 0.f;
            uv[c].x = valid ? u_.x : 0u;
            uv[c].y = valid ? u_.y : 0u;
        }
        float M = fmaxf(fmaxf(fmaxf(mv[0], mv[1]), fmaxf(mv[2], mv[3])),
                        fmaxf(fmaxf(mv[4], mv[5]), fmaxf(mv[6], mv[7])));
        float Sm = 0.f, a0 = 0.f, a1 = 0.f, a2 = 0.f, a3 = 0.f;
#pragma unroll
        for (int c = 0; c < 8; ++c) {
            float e = exp2f(mv[c] - M);
            Sm = fmaf(sv[c], e, Sm);
            a0 = fmaf(__uint_as_float(uv[c].x << 16), e, a0);
            a1 = fmaf(__uint_as_float(uv[c].x & 0xffff0000u), e, a1);
            a2 = fmaf(__uint_as_float(uv[c].y << 16), e, a2);
            a3 = fmaf(__uint_as_float(uv[c].y & 0xffff0000u), e, a3);
        }
        float inv = 1.f / Sm;
        uint2 o;
        o.x = cvtpk(a0 * inv, a1 * inv);
        o.y = cvtpk(a2 * inv, a3 * inv);
        *(uint2*)&Asb[token][16 * h + 4 * dq] = o;
    }
    __syncthreads();

    // ---- phase 2: oproj MFMA + bias + residual -> Os
    {
        f32x4 c = {0.f, 0.f, 0.f, 0.f};
#pragma unroll
        for (int ks = 0; ks < 2; ++ks) {
            s16x8 af = *(const s16x8*)&Asb[lane & 15][32 * ks + 8 * (lane >> 4)];
            s16x8 bf = *(const s16x8*)(wob + (((w * 2) + ks) * 64 + lane) * 4);
            c = __builtin_amdgcn_mfma_f32_16x16x32_bf16(af, bf, c, 0, 0, 0);
        }
        int j = 16 * w + (lane & 15);
        int q4 = lane >> 4;
        float boj = bo[j];
#pragma unroll
        for (int r = 0; r < 4; ++r) {
            int tk = q4 * 4 + r;
            Os[tk][j] = c[r] + boj + x[(size_t)(t0 + tk) * D + j];
        }
    }
    __syncthreads();

    // ---- phase 3: LN1 -> R1s + R1sb
    {
        int j = lane;
        float gj = g1[j], bj = bb1[j];
#pragma unroll
        for (int i = 0; i < 4; ++i) {
            int tk = w * 4 + i;
            float o = Os[tk][j];
            float mu = wave_sum(o) * (1.f / 64.f);
            float dif = o - mu;
            float var = wave_sum(dif * dif) * (1.f / 64.f);
            float r1 = dif * rsqrtf(var + 1e-5f) * gj + bj;
            R1s[tk][j] = r1;
            R1sb[tk][j] = f2bf(r1);
        }
    }
    __syncthreads();

    // ---- phase 4: FFN1 MFMA + b1 + relu -> Hhb
    {
        int q4 = lane >> 4;
#pragma unroll
        for (int t = 0; t < 4; ++t) {
            int ft = w * 4 + t;
            f32x4 c = {0.f, 0.f, 0.f, 0.f};
#pragma unroll
            for (int ks = 0; ks < 2; ++ks) {
                s16x8 af = *(const s16x8*)&R1sb[lane & 15][32 * ks + 8 * (lane >> 4)];
                s16x8 bf = *(const s16x8*)(w1b + (((ft * 2) + ks) * 64 + lane) * 4);
                c = __builtin_amdgcn_mfma_f32_16x16x32_bf16(af, bf, c, 0, 0, 0);
            }
            int f = 16 * ft + (lane & 15);
            float b1f = b1[f];
#pragma unroll
            for (int r = 0; r < 4; ++r)
                Hhb[q4 * 4 + r][f] = f2bf(fmaxf(c[r] + b1f, 0.f));
        }
    }
    __syncthreads();

    // ---- phase 5: FFN2 MFMA + b2 + residual -> Ys (Os reused)
    {
        f32x4 c = {0.f, 0.f, 0.f, 0.f};
#pragma unroll
        for (int ks = 0; ks < 8; ++ks) {
            s16x8 af = *(const s16x8*)&Hhb[lane & 15][32 * ks + 8 * (lane >> 4)];
            s16x8 bf = *(const s16x8*)(w2b + (((w * 8) + ks) * 64 + lane) * 4);
            c = __builtin_amdgcn_mfma_f32_16x16x32_bf16(af, bf, c, 0, 0, 0);
        }
        int j = 16 * w + (lane & 15);
        int q4 = lane >> 4;
        float b2j = b2[j];
#pragma unroll
        for (int r = 0; r < 4; ++r) {
            int tk = q4 * 4 + r;
            Os[tk][j] = c[r] + b2j + R1s[tk][j];
        }
    }
    __syncthreads();

    // ---- phase 6: LN2 -> out
    {
        int j = lane;
        float gj = g2[j], bj = bb2[j];
#pragma unroll
        for (int i = 0; i < 4; ++i) {
            int tk = w * 4 + i;
            float y = Os[tk][j];
            float mu = wave_sum(y) * (1.f / 64.f);
            float dif = y - mu;
            float var = wave_sum(dif * dif) * (1.f / 64.f);
            out[(size_t)(t0 + tk) * D + j] = dif * rsqrtf(var + 1e-5f) * gj + bj;
        }
    }
}

// ----------------------------------------------------------------
extern "C" void kernel_launch(void* const* d_in, const int* in_sizes, int n_in,
                              void* d_out, int out_size, void* d_ws, size_t ws_size,
                              hipStream_t stream)
{
    const float* x   = (const float*)d_in[0];
    const float* wq  = (const float*)d_in[1];
    const float* bq  = (const float*)d_in[2];
    const float* wk  = (const float*)d_in[3];
    const float* bk  = (const float*)d_in[4];
    const float* wv  = (const float*)d_in[5];
    const float* bv  = (const float*)d_in[6];
    const float* wo  = (const float*)d_in[7];
    const float* bo  = (const float*)d_in[8];
    const float* g1  = (const float*)d_in[9];
    const float* be1 = (const float*)d_in[10];
    const float* w1  = (const float*)d_in[11];
    const float* b1  = (const float*)d_in[12];
    const float* w2  = (const float*)d_in[13];
    const float* b2  = (const float*)d_in[14];
    const float* g2  = (const float*)d_in[15];
    const float* be2 = (const float*)d_in[16];

    char* base = (char*)d_ws;
    unsigned short* Qb  = (unsigned short*)base;                  // 1 MB
    unsigned short* Kb  = (unsigned short*)(base + (1u << 20));   // 1 MB
    unsigned short* Vtg = (unsigned short*)(base + (2u << 20));   // 1 MB
    float*          P   = (float*)(base + (3u << 20));            // 5.9 MB
    unsigned*       wob = (unsigned*)(base + (9u << 20));         // 8 KB
    unsigned*       w1b = (unsigned*)(base + (9u << 20) + 0x10000); // 32 KB
    unsigned*       w2b = (unsigned*)(base + (9u << 20) + 0x20000); // 32 KB

    k_qkv      <<<T / 32, 256, 0, stream>>>(x, wq, bq, wk, bk, wv, bv,
                                            wo, w1, w2, Qb, Kb, Vtg,
                                            wob, w1b, w2b);
    k_attn_part<<<NZ, 256, 0, stream>>>(Qb, Kb, Vtg, P);
    k_post     <<<T / 16, 256, 0, stream>>>(P, x, wob, bo, g1, be1,
                                            w1b, b1, w2b, b2, g2, be2,
                                            (float*)d_out);
}